// Round 5
// baseline (225.725 us; speedup 1.0000x reference)
//
#include <hip/hip_runtime.h>

#define NL 7
#define NA 32
#define PERL 528
#define NF 3696
#define SQRT2f 1.41421356237309515f

typedef __attribute__((ext_vector_type(8))) short bf16x8;
typedef __attribute__((ext_vector_type(16))) float f32x16;

__device__ __forceinline__ unsigned f2bf(float f) {
    union { float f; unsigned u; } c; c.f = f;
    return (c.u + 0x7fffu + ((c.u >> 16) & 1u)) >> 16;   // RNE to bf16
}

__global__ __launch_bounds__(256) void ps_kernel(
    const float* __restrict__ se0, const float* __restrict__ se1,
    const float* __restrict__ se2, const float* __restrict__ se3,
    const float* __restrict__ se4, const float* __restrict__ se5,
    const float* __restrict__ se6, float* __restrict__ out)
{
    __shared__ __align__(16) float LB[NF];   // 14784 B: raw staging (first 1568), then output
    __shared__ float s_wsum[4];
    __shared__ float s_inv;

    const int j   = blockIdx.x;
    const int tid = threadIdx.x;

    // ---- phase 1: raw f32 staging, fully coalesced, no conversion ----
    #pragma unroll
    for (int k = 0; k < 2; ++k) {
        const int g = tid + k * 256;
        if (g < 392) {
            const int e0 = 4 * g;
            const float* srcp;
            if      (e0 <  32) srcp = se0 + (size_t)j *  32 + e0;
            else if (e0 < 128) srcp = se1 + (size_t)j *  96 + (e0 - 32);
            else if (e0 < 288) srcp = se2 + (size_t)j * 160 + (e0 - 128);
            else if (e0 < 512) srcp = se3 + (size_t)j * 224 + (e0 - 288);
            else if (e0 < 800) srcp = se4 + (size_t)j * 288 + (e0 - 512);
            else if (e0 <1152) srcp = se5 + (size_t)j * 352 + (e0 - 800);
            else               srcp = se6 + (size_t)j * 416 + (e0 - 1152);
            *(float4*)(LB + e0) = *(const float4*)srcp;
        }
    }
    __syncthreads();   // B1

    // ---- phase 2: per-wave 32x32x16 MFMA Gram (l = wv and wv+4) ----
    const int wv   = tid >> 6;
    const int lane = tid & 63;
    const int row  = lane & 31;
    const int k0   = (lane >> 5) * 8;

    const int lA = wv;
    const int lB = wv + 4;

    f32x16 accA, accB;
    #pragma unroll
    for (int r = 0; r < 16; ++r) { accA[r] = 0.0f; accB[r] = 0.0f; }

    auto gather = [&](int l) -> bf16x8 {
        const int m21 = 2 * l + 1;
        const float sg = rsqrtf(sqrtf((float)m21));     // (2l+1)^(-1/4), folded twice = 1/sqrt(2l+1)
        const float* rp = LB + 32 * l * l + row * m21 + k0;
        unsigned pk[4];
        #pragma unroll
        for (int p = 0; p < 4; ++p) {
            const float t0 = rp[2 * p];                  // unconditional (in-bounds of LB)
            const float t1 = rp[2 * p + 1];
            const float v0 = (k0 + 2 * p     < m21) ? t0 * sg : 0.0f;
            const float v1 = (k0 + 2 * p + 1 < m21) ? t1 * sg : 0.0f;
            pk[p] = f2bf(v0) | (f2bf(v1) << 16);
        }
        union { unsigned u[4]; bf16x8 v; } cv;
        cv.u[0] = pk[0]; cv.u[1] = pk[1]; cv.u[2] = pk[2]; cv.u[3] = pk[3];
        return cv.v;
    };

    {
        const bf16x8 fA = gather(lA);
        accA = __builtin_amdgcn_mfma_f32_32x32x16_bf16(fA, fA, accA, 0, 0, 0);
    }
    if (lB < NL) {
        const bf16x8 fB = gather(lB);
        accB = __builtin_amdgcn_mfma_f32_32x32x16_bf16(fB, fB, accB, 0, 0, 0);
    }

    // ---- phase 3: Frobenius ssq (diag^2 + 2*upper^2 exactly) ----
    float ssq = 0.0f;
    #pragma unroll
    for (int r = 0; r < 16; ++r) ssq += accA[r] * accA[r] + accB[r] * accB[r];

    #pragma unroll
    for (int off = 32; off >= 1; off >>= 1) ssq += __shfl_down(ssq, off, 64);
    if (lane == 0) s_wsum[wv] = ssq;
    __syncthreads();   // B2: all staging reads done, wsum ready

    if (tid == 0) {
        const float tot = s_wsum[0] + s_wsum[1] + s_wsum[2] + s_wsum[3];
        s_inv = 1.0f / fmaxf(sqrtf(tot), 1e-12f);
    }

    // ---- phase 4: scatter into LDS output buffer (reuses LB) ----
    // C layout (verified): col = lane&31, row = (reg&3) + 8*(reg>>2) + 4*(lane>>5)
    const int col = lane & 31;
    const int hi4 = (lane >> 5) * 4;
    auto scatter = [&](const f32x16& g, int l) {
        float* ol = LB + l * PERL;
        #pragma unroll
        for (int r = 0; r < 16; ++r) {
            const int rw = (r & 3) + 8 * (r >> 2) + hi4;
            const float v = g[r];
            if (rw == col)      ol[rw] = v;
            else if (rw < col)  ol[32 + (rw * (63 - rw)) / 2 + (col - rw - 1)] = v * SQRT2f;
        }
    };
    scatter(accA, lA);
    if (lB < NL) scatter(accB, lB);
    __syncthreads();   // B3

    // ---- phase 5: coalesced normalized output ----
    const float inv = s_inv;
    const float4* ob4 = (const float4*)LB;
    float4* op4 = (float4*)(out + (size_t)j * NF);
    #pragma unroll
    for (int k = 0; k < 4; ++k) {
        const int q = tid + k * 256;
        if (q < 924) {
            float4 v = ob4[q];
            v.x *= inv; v.y *= inv; v.z *= inv; v.w *= inv;
            op4[q] = v;
        }
    }
}

extern "C" void kernel_launch(void* const* d_in, const int* in_sizes, int n_in,
                              void* d_out, int out_size, void* d_ws, size_t ws_size,
                              hipStream_t stream) {
    const float* se0 = (const float*)d_in[0];
    const float* se1 = (const float*)d_in[1];
    const float* se2 = (const float*)d_in[2];
    const float* se3 = (const float*)d_in[3];
    const float* se4 = (const float*)d_in[4];
    const float* se5 = (const float*)d_in[5];
    const float* se6 = (const float*)d_in[6];
    float* out = (float*)d_out;

    const int J = in_sizes[0] / NA;   // se_0 is (J, 32, 1)
    ps_kernel<<<J, 256, 0, stream>>>(se0, se1, se2, se3, se4, se5, se6, out);
}

// Round 6
// 206.769 us; speedup vs baseline: 1.0917x; 1.0917x over previous
//
#include <hip/hip_runtime.h>

#define NL 7
#define NA 32
#define PERL 528
#define NF 3696
#define RSH 24                   // halves per staged row (48 B, 16B-aligned, 4-way max conflict)
#define SQRT2f 1.41421356237309515f

typedef __attribute__((ext_vector_type(8))) short bf16x8;
typedef __attribute__((ext_vector_type(16))) float f32x16;
typedef float f32x4u __attribute__((ext_vector_type(4), aligned(4)));

__device__ __forceinline__ unsigned f2bf(float f) {
    union { float f; unsigned u; } c; c.f = f;
    return (c.u + 0x7fffu + ((c.u >> 16) & 1u)) >> 16;   // RNE to bf16
}

// Stage one (l,a) row: load m21 floats, scale by (2l+1)^(-1/4), pad to 16 bf16 halves.
// All indices compile-time (constexpr m21) -> buf stays in registers.
#define STAGE_CASE(L, SE, SGL) {                                                \
    constexpr int m21 = 2 * (L) + 1;                                            \
    const float* src = (SE) + (size_t)j * (32 * m21) + a * m21;                 \
    float buf[16];                                                              \
    _Pragma("unroll") for (int i = 0; i < 16; ++i) buf[i] = 0.0f;               \
    if constexpr (m21 < 4) {                                                    \
        _Pragma("unroll") for (int m = 0; m < m21; ++m) buf[m] = src[m];        \
    } else {                                                                    \
        constexpr int nf = m21 >> 2;                                            \
        _Pragma("unroll") for (int q = 0; q < nf; ++q) {                        \
            f32x4u v = *(const f32x4u*)(src + 4 * q);                           \
            _Pragma("unroll") for (int i = 0; i < 4; ++i) buf[4 * q + i] = v[i];\
        }                                                                       \
        {   f32x4u v = *(const f32x4u*)(src + m21 - 4);                         \
            _Pragma("unroll") for (int i = 0; i < 4; ++i) buf[m21 - 4 + i] = v[i]; } \
    }                                                                           \
    unsigned pk[8];                                                             \
    _Pragma("unroll") for (int p = 0; p < 8; ++p)                               \
        pk[p] = f2bf(buf[2 * p] * (SGL)) | (f2bf(buf[2 * p + 1] * (SGL)) << 16);\
    unsigned short* rowp = Th + ((L) * 32 + a) * RSH;                           \
    *(uint4*)(rowp)     = make_uint4(pk[0], pk[1], pk[2], pk[3]);               \
    *(uint4*)(rowp + 8) = make_uint4(pk[4], pk[5], pk[6], pk[7]);               \
}

__global__ __launch_bounds__(256) void ps_kernel(
    const float* __restrict__ se0, const float* __restrict__ se1,
    const float* __restrict__ se2, const float* __restrict__ se3,
    const float* __restrict__ se4, const float* __restrict__ se5,
    const float* __restrict__ se6, float* __restrict__ out)
{
    __shared__ __align__(16) float LB[NF];   // 14784 B: staged bf16 rows (first 10752 B), then output
    __shared__ float s_wsum[4];
    __shared__ float s_inv;
    unsigned short* Th = (unsigned short*)LB;

    const int j   = blockIdx.x;
    const int tid = threadIdx.x;

    // ---- phase 1: row-wise staging, conversion + (2l+1)^(-1/4) scale folded ----
    if (tid < 224) {
        const int a = tid & 31;
        switch (tid >> 5) {
            case 0: STAGE_CASE(0, se0, 1.0f);           break;
            case 1: STAGE_CASE(1, se1, 0.7598356857f);  break;
            case 2: STAGE_CASE(2, se2, 0.6687403050f);  break;
            case 3: STAGE_CASE(3, se3, 0.6147881526f);  break;
            case 4: STAGE_CASE(4, se4, 0.5773502692f);  break;
            case 5: STAGE_CASE(5, se5, 0.5491004040f);  break;
            case 6: STAGE_CASE(6, se6, 0.5266403878f);  break;
        }
    }
    __syncthreads();   // B1

    // ---- phase 2: per-wave 32x32x16 MFMA Gram (l = wv and wv+4) ----
    const int wv   = tid >> 6;
    const int lane = tid & 63;
    const int row  = lane & 31;
    const int hoff = (lane >> 5) * 8;    // k half-offset 0/8

    const int lA = wv;
    const int lB = wv + 4;

    f32x16 accA, accB;
    #pragma unroll
    for (int r = 0; r < 16; ++r) { accA[r] = 0.0f; accB[r] = 0.0f; }

    {
        const bf16x8 fA = *(const bf16x8*)(Th + (lA * 32 + row) * RSH + hoff);
        accA = __builtin_amdgcn_mfma_f32_32x32x16_bf16(fA, fA, accA, 0, 0, 0);
    }
    if (lB < NL) {
        const bf16x8 fB = *(const bf16x8*)(Th + (lB * 32 + row) * RSH + hoff);
        accB = __builtin_amdgcn_mfma_f32_32x32x16_bf16(fB, fB, accB, 0, 0, 0);
    }

    // ---- phase 3: Frobenius ssq (diag^2 + 2*upper^2 via full symmetric sum) ----
    float ssq = 0.0f;
    #pragma unroll
    for (int r = 0; r < 16; ++r) ssq += accA[r] * accA[r] + accB[r] * accB[r];

    #pragma unroll
    for (int off = 32; off >= 1; off >>= 1) ssq += __shfl_down(ssq, off, 64);
    if (lane == 0) s_wsum[wv] = ssq;
    __syncthreads();   // B2: frag reads done, wsum ready

    if (tid == 0) {
        const float tot = s_wsum[0] + s_wsum[1] + s_wsum[2] + s_wsum[3];
        s_inv = 1.0f / fmaxf(sqrtf(tot), 1e-12f);
    }

    // ---- phase 4: transpose-scatter into LDS output buffer (reuses LB) ----
    // C layout: col = lane&31, row = (r&3)+8*(r>>2)+4*(lane>>5). G symmetric ->
    // lane owns OUTPUT row c = lane&31, columns rw; upper offset = ubase + rw.
    const int c     = lane & 31;
    const int hi4   = (lane >> 5) * 4;
    const int ubase = 32 + (c * (63 - c)) / 2 - c - 1;

    {
        float* ol = LB + lA * PERL;
        #pragma unroll
        for (int r = 0; r < 16; ++r) {
            const int rw = (r & 3) + 8 * (r >> 2) + hi4;
            if (rw >= c) {
                const bool d = (rw == c);
                ol[d ? c : (ubase + rw)] = d ? accA[r] : accA[r] * SQRT2f;
            }
        }
    }
    if (lB < NL) {
        float* ol = LB + lB * PERL;
        #pragma unroll
        for (int r = 0; r < 16; ++r) {
            const int rw = (r & 3) + 8 * (r >> 2) + hi4;
            if (rw >= c) {
                const bool d = (rw == c);
                ol[d ? c : (ubase + rw)] = d ? accB[r] : accB[r] * SQRT2f;
            }
        }
    }
    __syncthreads();   // B3

    // ---- phase 5: coalesced normalized output ----
    const float inv = s_inv;
    const float4* ob4 = (const float4*)LB;
    float4* op4 = (float4*)(out + (size_t)j * NF);
    #pragma unroll
    for (int k = 0; k < 4; ++k) {
        const int q = tid + k * 256;
        if (q < 924) {
            float4 v = ob4[q];
            v.x *= inv; v.y *= inv; v.z *= inv; v.w *= inv;
            op4[q] = v;
        }
    }
}

extern "C" void kernel_launch(void* const* d_in, const int* in_sizes, int n_in,
                              void* d_out, int out_size, void* d_ws, size_t ws_size,
                              hipStream_t stream) {
    const float* se0 = (const float*)d_in[0];
    const float* se1 = (const float*)d_in[1];
    const float* se2 = (const float*)d_in[2];
    const float* se3 = (const float*)d_in[3];
    const float* se4 = (const float*)d_in[4];
    const float* se5 = (const float*)d_in[5];
    const float* se6 = (const float*)d_in[6];
    float* out = (float*)d_out;

    const int J = in_sizes[0] / NA;   // se_0 is (J, 32, 1)
    ps_kernel<<<J, 256, 0, stream>>>(se0, se1, se2, se3, se4, se5, se6, out);
}

// Round 8
// 202.701 us; speedup vs baseline: 1.1136x; 1.0201x over previous
//
#include <hip/hip_runtime.h>

#define NL 7
#define NA 32
#define PERL 528
#define NF 3696
#define RSH 24                   // halves per staged row (48 B, 16B-aligned)
#define SQRT2f 1.41421356237309515f

typedef __attribute__((ext_vector_type(8))) short bf16x8;
typedef __attribute__((ext_vector_type(16))) float f32x16;
typedef __attribute__((ext_vector_type(4))) float nf4;   // native vector for nt-store
typedef float f32x4u __attribute__((ext_vector_type(4), aligned(4)));

__device__ __forceinline__ unsigned f2bf(float f) {
    union { float f; unsigned u; } c; c.f = f;
    return (c.u + 0x7fffu + ((c.u >> 16) & 1u)) >> 16;   // RNE to bf16
}

// Stage one (l,a) row: load m21 floats, scale by (2l+1)^(-1/4), pad to 16 bf16 halves.
#define STAGE_CASE(L, SE, SGL) {                                                \
    constexpr int m21 = 2 * (L) + 1;                                            \
    const float* src = (SE) + (size_t)j * (32 * m21) + a * m21;                 \
    float buf[16];                                                              \
    _Pragma("unroll") for (int i = 0; i < 16; ++i) buf[i] = 0.0f;               \
    if constexpr (m21 < 4) {                                                    \
        _Pragma("unroll") for (int m = 0; m < m21; ++m) buf[m] = src[m];        \
    } else {                                                                    \
        constexpr int nf = m21 >> 2;                                            \
        _Pragma("unroll") for (int q = 0; q < nf; ++q) {                        \
            f32x4u v = *(const f32x4u*)(src + 4 * q);                           \
            _Pragma("unroll") for (int i = 0; i < 4; ++i) buf[4 * q + i] = v[i];\
        }                                                                       \
        {   f32x4u v = *(const f32x4u*)(src + m21 - 4);                         \
            _Pragma("unroll") for (int i = 0; i < 4; ++i) buf[m21 - 4 + i] = v[i]; } \
    }                                                                           \
    unsigned pk[8];                                                             \
    _Pragma("unroll") for (int p = 0; p < 8; ++p)                               \
        pk[p] = f2bf(buf[2 * p] * (SGL)) | (f2bf(buf[2 * p + 1] * (SGL)) << 16);\
    unsigned short* rowp = Th + ((L) * 32 + a) * RSH;                           \
    *(uint4*)(rowp)     = make_uint4(pk[0], pk[1], pk[2], pk[3]);               \
    *(uint4*)(rowp + 8) = make_uint4(pk[4], pk[5], pk[6], pk[7]);               \
}

__global__ __launch_bounds__(256) void ps_kernel(
    const float* __restrict__ se0, const float* __restrict__ se1,
    const float* __restrict__ se2, const float* __restrict__ se3,
    const float* __restrict__ se4, const float* __restrict__ se5,
    const float* __restrict__ se6, float* __restrict__ out)
{
    __shared__ __align__(16) float LB[NF];   // staging (first 10752 B) then output buffer
    __shared__ float s_wsum[4];
    __shared__ float s_inv;
    unsigned short* Th = (unsigned short*)LB;

    const int j   = blockIdx.x;
    const int tid = threadIdx.x;

    // ---- phase 1: row-wise staging, conversion + (2l+1)^(-1/4) scale folded ----
    if (tid < 224) {
        const int a = tid & 31;
        switch (tid >> 5) {
            case 0: STAGE_CASE(0, se0, 1.0f);           break;
            case 1: STAGE_CASE(1, se1, 0.7598356857f);  break;
            case 2: STAGE_CASE(2, se2, 0.6687403050f);  break;
            case 3: STAGE_CASE(3, se3, 0.6147881526f);  break;
            case 4: STAGE_CASE(4, se4, 0.5773502692f);  break;
            case 5: STAGE_CASE(5, se5, 0.5491004040f);  break;
            case 6: STAGE_CASE(6, se6, 0.5266403878f);  break;
        }
    }
    __syncthreads();   // B1

    // ---- phase 2: per-wave 32x32x16 MFMA Gram (l = wv and wv+4) ----
    const int wv   = tid >> 6;
    const int lane = tid & 63;
    const int row  = lane & 31;
    const int hoff = (lane >> 5) * 8;    // k half-offset 0/8

    const int lA = wv;
    const int lB = wv + 4;

    f32x16 accA, accB;
    #pragma unroll
    for (int r = 0; r < 16; ++r) { accA[r] = 0.0f; accB[r] = 0.0f; }

    {
        const bf16x8 fA = *(const bf16x8*)(Th + (lA * 32 + row) * RSH + hoff);
        accA = __builtin_amdgcn_mfma_f32_32x32x16_bf16(fA, fA, accA, 0, 0, 0);
    }
    if (lB < NL) {
        const bf16x8 fB = *(const bf16x8*)(Th + (lB * 32 + row) * RSH + hoff);
        accB = __builtin_amdgcn_mfma_f32_32x32x16_bf16(fB, fB, accB, 0, 0, 0);
    }

    // ---- phase 3: Frobenius ssq (diag^2 + 2*upper^2 via full symmetric sum) ----
    float ssq = 0.0f;
    #pragma unroll
    for (int r = 0; r < 16; ++r) ssq += accA[r] * accA[r] + accB[r] * accB[r];

    #pragma unroll
    for (int off = 32; off >= 1; off >>= 1) ssq += __shfl_down(ssq, off, 64);
    if (lane == 0) s_wsum[wv] = ssq;
    __syncthreads();   // B2: frag reads done, wsum ready

    if (tid == 0) {
        const float tot = s_wsum[0] + s_wsum[1] + s_wsum[2] + s_wsum[3];
        s_inv = 1.0f / fmaxf(sqrtf(tot), 1e-12f);
    }

    // ---- phase 4: transpose-scatter into LDS output buffer (reuses LB) ----
    // C layout: col = lane&31, row = (r&3)+8*(r>>2)+4*(lane>>5). G symmetric ->
    // lane owns OUTPUT row c = lane&31, columns rw; upper offset = ubase + rw.
    const int c     = lane & 31;
    const int hi4   = (lane >> 5) * 4;
    const int ubase = 32 + (c * (63 - c)) / 2 - c - 1;

    {
        float* ol = LB + lA * PERL;
        #pragma unroll
        for (int r = 0; r < 16; ++r) {
            const int rw = (r & 3) + 8 * (r >> 2) + hi4;
            if (rw >= c) {
                const bool d = (rw == c);
                ol[d ? c : (ubase + rw)] = d ? accA[r] : accA[r] * SQRT2f;
            }
        }
    }
    if (lB < NL) {
        float* ol = LB + lB * PERL;
        #pragma unroll
        for (int r = 0; r < 16; ++r) {
            const int rw = (r & 3) + 8 * (r >> 2) + hi4;
            if (rw >= c) {
                const bool d = (rw == c);
                ol[d ? c : (ubase + rw)] = d ? accB[r] : accB[r] * SQRT2f;
            }
        }
    }
    __syncthreads();   // B3

    // ---- phase 5: coalesced normalized output, NONTEMPORAL (no L2/L3 allocate) ----
    const float inv = s_inv;
    const nf4* ob4 = (const nf4*)LB;
    nf4* op4 = (nf4*)(out + (size_t)j * NF);
    #pragma unroll
    for (int k = 0; k < 4; ++k) {
        const int q = tid + k * 256;
        if (q < 924) {
            nf4 v = ob4[q];
            v *= inv;
            __builtin_nontemporal_store(v, &op4[q]);
        }
    }
}

extern "C" void kernel_launch(void* const* d_in, const int* in_sizes, int n_in,
                              void* d_out, int out_size, void* d_ws, size_t ws_size,
                              hipStream_t stream) {
    const float* se0 = (const float*)d_in[0];
    const float* se1 = (const float*)d_in[1];
    const float* se2 = (const float*)d_in[2];
    const float* se3 = (const float*)d_in[3];
    const float* se4 = (const float*)d_in[4];
    const float* se5 = (const float*)d_in[5];
    const float* se6 = (const float*)d_in[6];
    float* out = (float*)d_out;

    const int J = in_sizes[0] / NA;   // se_0 is (J, 32, 1)
    ps_kernel<<<J, 256, 0, stream>>>(se0, se1, se2, se3, se4, se5, se6, out);
}

// Round 9
// 198.502 us; speedup vs baseline: 1.1371x; 1.0212x over previous
//
#include <hip/hip_runtime.h>

#define NL 7
#define NA 32
#define PERL 528
#define NF 3696
#define RSH 24                   // halves per staged row (48 B stride, 16B-aligned)
#define SQRT2f 1.41421356237309515f

typedef short bf16x8 __attribute__((ext_vector_type(8)));
typedef float f32x16 __attribute__((ext_vector_type(16)));
typedef unsigned uint4v __attribute__((ext_vector_type(4)));
typedef float f32x4u __attribute__((ext_vector_type(4), aligned(4)));

__device__ __forceinline__ unsigned cvtpk(float lo, float hi) {
    unsigned r;
    asm("v_cvt_pk_bf16_f32 %0, %1, %2" : "=v"(r) : "v"(lo), "v"(hi));
    return r;
}

// Stage full 16-half row (l,a) for m21 <= 7 (second uint4 all zero).
template<int L>
__device__ __forceinline__ void stage_lo(const float* __restrict__ se, int j, int a,
                                         unsigned short* __restrict__ Th) {
    constexpr int m21 = 2 * L + 1;
    const float* rowp = se + (size_t)j * (32 * m21) + a * m21;
    float v[8];
    #pragma unroll
    for (int i = 0; i < 8; ++i) v[i] = 0.0f;
    if constexpr (m21 == 1) { v[0] = rowp[0]; }
    else if constexpr (m21 == 3) {
        f32x4u t = *(const f32x4u*)rowp;                 // 1-elem overread into next row (page-safe)
        v[0] = t[0]; v[1] = t[1]; v[2] = t[2];
    } else if constexpr (m21 == 5) {
        f32x4u t = *(const f32x4u*)rowp;
        v[0] = t[0]; v[1] = t[1]; v[2] = t[2]; v[3] = t[3];
        v[4] = rowp[4];
    } else {                                             // m21 == 7, overlap trick, no overread
        f32x4u t0 = *(const f32x4u*)rowp;
        f32x4u t1 = *(const f32x4u*)(rowp + 3);
        v[0] = t0[0]; v[1] = t0[1]; v[2] = t0[2];
        v[3] = t1[0]; v[4] = t1[1]; v[5] = t1[2]; v[6] = t1[3];
    }
    unsigned pk[4];
    #pragma unroll
    for (int p = 0; p < 4; ++p) pk[p] = (2 * p < m21) ? cvtpk(v[2 * p], v[2 * p + 1]) : 0u;
    unsigned short* rp = Th + (L * 32 + a) * RSH;
    *(uint4*)rp       = make_uint4(pk[0], pk[1], pk[2], pk[3]);
    *(uint4*)(rp + 8) = make_uint4(0u, 0u, 0u, 0u);
}

// Stage full 16-half row (l,a) for m21 in {9,11,13}.
template<int L>
__device__ __forceinline__ void stage_hi(const float* __restrict__ se, int j, int a,
                                         unsigned short* __restrict__ Th) {
    constexpr int m21 = 2 * L + 1;
    const float* rowp = se + (size_t)j * (32 * m21) + a * m21;
    float v[16];
    #pragma unroll
    for (int i = 0; i < 16; ++i) v[i] = 0.0f;
    {
        f32x4u t0 = *(const f32x4u*)rowp;
        f32x4u t1 = *(const f32x4u*)(rowp + 4);
        #pragma unroll
        for (int i = 0; i < 4; ++i) { v[i] = t0[i]; v[4 + i] = t1[i]; }
    }
    if constexpr (m21 == 9) { v[8] = rowp[8]; }
    else if constexpr (m21 == 11) {
        f32x4u t = *(const f32x4u*)(rowp + 7);           // elems 7..10, overlap, no overread
        v[8] = t[1]; v[9] = t[2]; v[10] = t[3];
    } else {                                             // m21 == 13
        f32x4u t = *(const f32x4u*)(rowp + 8);
        v[8] = t[0]; v[9] = t[1]; v[10] = t[2]; v[11] = t[3];
        v[12] = rowp[12];
    }
    unsigned pk[8];
    #pragma unroll
    for (int p = 0; p < 8; ++p) pk[p] = (2 * p < m21) ? cvtpk(v[2 * p], v[2 * p + 1]) : 0u;
    unsigned short* rp = Th + (L * 32 + a) * RSH;
    *(uint4*)rp       = make_uint4(pk[0], pk[1], pk[2], pk[3]);
    *(uint4*)(rp + 8) = make_uint4(pk[4], pk[5], pk[6], pk[7]);
}

__global__ __launch_bounds__(256) void ps_kernel(
    const float* __restrict__ se0, const float* __restrict__ se1,
    const float* __restrict__ se2, const float* __restrict__ se3,
    const float* __restrict__ se4, const float* __restrict__ se5,
    const float* __restrict__ se6, float* __restrict__ out)
{
    __shared__ __align__(16) float LB[NF];   // staging bf16 rows (first 10752 B), then output
    __shared__ float s_wsum[4];
    unsigned short* Th = (unsigned short*)LB;

    const int j    = blockIdx.x;
    const int tid  = threadIdx.x;
    const int wv   = tid >> 6;
    const int lane = tid & 63;

    // ---- phase 1: WAVE-LOCAL staging (each wave stages exactly the rows it consumes) ----
    {
        const int a = lane & 31;
        if (lane < 32) {
            switch (wv) {
                case 0:  stage_lo<0>(se0, j, a, Th); break;
                case 1:  stage_lo<1>(se1, j, a, Th); break;
                case 2:  stage_lo<2>(se2, j, a, Th); break;
                default: stage_lo<3>(se3, j, a, Th); break;
            }
        } else {
            switch (wv) {
                case 0:  stage_hi<4>(se4, j, a, Th); break;
                case 1:  stage_hi<5>(se5, j, a, Th); break;
                case 2:  stage_hi<6>(se6, j, a, Th); break;
                default: break;
            }
        }
    }
    // intra-wave LDS RAW: DS ops are per-wave in-order; fence the compiler only.
    __builtin_amdgcn_wave_barrier();
    asm volatile("" ::: "memory");

    // ---- phase 2: per-wave 32x32x16 MFMA Gram (l = wv and wv+4), raw values ----
    const int row  = lane & 31;
    const int hoff = (lane >> 5) * 8;
    const int lA = wv;
    const int lB = wv + 4;

    f32x16 accA, accB;
    #pragma unroll
    for (int r = 0; r < 16; ++r) { accA[r] = 0.0f; accB[r] = 0.0f; }

    {
        const bf16x8 fA = *(const bf16x8*)(Th + (lA * 32 + row) * RSH + hoff);
        accA = __builtin_amdgcn_mfma_f32_32x32x16_bf16(fA, fA, accA, 0, 0, 0);
    }
    if (lB < NL) {
        const bf16x8 fB = *(const bf16x8*)(Th + (lB * 32 + row) * RSH + hoff);
        accB = __builtin_amdgcn_mfma_f32_32x32x16_bf16(fB, fB, accB, 0, 0, 0);
    }

    // ---- phase 3: ssq with exact 1/(2l+1) weights ----
    const float rsA = rsqrtf((float)(2 * lA + 1));
    const float rsB = rsqrtf((float)(2 * lB + 1));
    float sA = 0.0f, sB = 0.0f;
    #pragma unroll
    for (int r = 0; r < 16; ++r) { sA += accA[r] * accA[r]; sB += accB[r] * accB[r]; }
    float ssq = sA * (rsA * rsA) + ((lB < NL) ? sB * (rsB * rsB) : 0.0f);

    #pragma unroll
    for (int off = 32; off >= 1; off >>= 1) ssq += __shfl_down(ssq, off, 64);
    if (lane == 0) s_wsum[wv] = ssq;
    __syncthreads();   // B2: staging reads done everywhere, wsum ready

    // every thread computes inv (no tid0 serialization, no extra barrier)
    const float tot = s_wsum[0] + s_wsum[1] + s_wsum[2] + s_wsum[3];
    const float inv = 1.0f / fmaxf(sqrtf(tot), 1e-12f);

    // ---- phase 4: scatter with rs*inv*(sqrt2) folded; reuses LB as output buffer ----
    const int c     = lane & 31;
    const int hi4   = (lane >> 5) * 4;
    const int ubase = 32 + (c * (63 - c)) / 2 - c - 1;

    {
        const float dsc = rsA * inv, usc = dsc * SQRT2f;
        float* ol = LB + lA * PERL;
        #pragma unroll
        for (int r = 0; r < 16; ++r) {
            const int rw = (r & 3) + 8 * (r >> 2) + hi4;
            if (rw >= c) {
                const bool d = (rw == c);
                ol[d ? c : (ubase + rw)] = accA[r] * (d ? dsc : usc);
            }
        }
    }
    if (lB < NL) {
        const float dsc = rsB * inv, usc = dsc * SQRT2f;
        float* ol = LB + lB * PERL;
        #pragma unroll
        for (int r = 0; r < 16; ++r) {
            const int rw = (r & 3) + 8 * (r >> 2) + hi4;
            if (rw >= c) {
                const bool d = (rw == c);
                ol[d ? c : (ubase + rw)] = accB[r] * (d ? dsc : usc);
            }
        }
    }
    __syncthreads();   // B3

    // ---- phase 5: pure coalesced nontemporal copy (values already normalized) ----
    const uint4v* ob4 = (const uint4v*)LB;
    uint4v* op4 = (uint4v*)(out + (size_t)j * NF);
    #pragma unroll
    for (int k = 0; k < 4; ++k) {
        const int q = tid + k * 256;
        if (q < 924) {
            uint4v v = ob4[q];
            __builtin_nontemporal_store(v, &op4[q]);
        }
    }
}

extern "C" void kernel_launch(void* const* d_in, const int* in_sizes, int n_in,
                              void* d_out, int out_size, void* d_ws, size_t ws_size,
                              hipStream_t stream) {
    const float* se0 = (const float*)d_in[0];
    const float* se1 = (const float*)d_in[1];
    const float* se2 = (const float*)d_in[2];
    const float* se3 = (const float*)d_in[3];
    const float* se4 = (const float*)d_in[4];
    const float* se5 = (const float*)d_in[5];
    const float* se6 = (const float*)d_in[6];
    float* out = (float*)d_out;

    const int J = in_sizes[0] / NA;   // se_0 is (J, 32, 1)
    ps_kernel<<<J, 256, 0, stream>>>(se0, se1, se2, se3, se4, se5, se6, out);
}